// Round 5
// baseline (61.700 us; speedup 1.0000x reference)
//
#include <hip/hip_runtime.h>

// GraphUpSample: per-node Linear(3->6) over 16 nodes + static column gather
// (the reference's aliased in-place column loop collapses to out col <- SRC[col]).
//
// R5: barrier-free wave-private streaming pipeline.
//  - each wave owns 64 consecutive rows = 4 tiles x 16 rows
//  - single per-wave LDS tile, rows padded to 52 floats (bank bases all distinct)
//  - pipeline: load regs(t+1) -> compute/store(t) -> ds_write(t+1); same-wave
//    in-order LDS => NO __syncthreads anywhere
//  - weights in 12 float4 registers (L1-resident loads, amortized over 64 rows)

#define BATCH 8192
#define FEAT  64
#define BF_TOTAL (BATCH * FEAT)      // 524288 rows
#define THREADS 256                  // 4 waves
#define TILE_ROWS 16
#define TILES 4                      // per wave: 64 rows
#define XROWF 52                     // padded floats per row (13 float4)

__constant__ int c_SRC[32] = {
    0, 2, 4, 6, 8, 10, 12, 14,
    1, 5, 9, 13, 3, 11, 7, 15,
    1, 3, 5, 7, 9, 11, 13, 15,
    3, 7, 11, 15, 7, 15, 15, 31
};

__global__ __launch_bounds__(THREADS)
void GraphUpSample_12120397709982_kernel(const float* __restrict__ x,
                                         const float* __restrict__ W,
                                         const float* __restrict__ bia,
                                         float* __restrict__ out)
{
    __shared__ float xs[4 * TILE_ROWS * XROWF];   // 4 waves x 3328 B = 13312 B

    const int tid  = threadIdx.x;
    const int widx = tid >> 6;
    const int lane = tid & 63;
    const int fc0  = lane & 7;       // column group: cols 4*fc0 .. 4*fc0+3
    const int rset = lane >> 3;      // 0..7 within tile
    const long long wid = (long long)blockIdx.x * 4 + widx;
    const long long rowbase = wid * 64;

    // ---- weights -> registers (tiny, L1/L2-resident, once per 64 rows) ----
    int    nn[4];
    float4 wr[3][4];
#pragma unroll
    for (int s = 0; s < 4; ++s) {
        const int src = c_SRC[fc0 * 4 + s];
        const int n   = src >> 1;
        const int m   = src & 1;
        nn[s] = n;
#pragma unroll
        for (int c = 0; c < 3; ++c) {
            const float* wp = W + (n * 6 + 2 * c + m) * 3;
            wr[c][s] = make_float4(wp[0], wp[1], wp[2], bia[n * 6 + 2 * c + m]);
        }
    }

    float*  wlds  = xs + widx * (TILE_ROWS * XROWF);
    float4* wlds4 = (float4*)wlds;
    const float4* xg = (const float4*)(x + rowbase * 48);
    float4*       og = (float4*)(out + rowbase * 96);

    // ---- prologue: stage tile 0 ----
    float4 stg[3];
#pragma unroll
    for (int i = 0; i < 3; ++i) stg[i] = xg[lane + 64 * i];
#pragma unroll
    for (int i = 0; i < 3; ++i) {
        const int p = lane + 64 * i, row = p / 12, k = p - row * 12;
        wlds4[row * 13 + k] = stg[i];
    }

#pragma unroll
    for (int t = 0; t < TILES; ++t) {
        // issue next tile's global loads early (hide HBM latency under compute)
        float4 nxt[3];
        if (t < TILES - 1) {
#pragma unroll
            for (int i = 0; i < 3; ++i)
                nxt[i] = xg[(t + 1) * 192 + lane + 64 * i];
        }

        // compute + store tile t from LDS
#pragma unroll
        for (int rr = 0; rr < 2; ++rr) {
            const int row = rset + rr * 8;
            const float* xr = wlds + row * XROWF;

            float xv[3][4];
#pragma unroll
            for (int cp = 0; cp < 3; ++cp)
#pragma unroll
                for (int s = 0; s < 4; ++s)
                    xv[cp][s] = xr[cp * 16 + nn[s]];

#pragma unroll
            for (int c = 0; c < 3; ++c) {
                float4 o4;
                o4.x = fmaf(xv[0][0], wr[c][0].x, fmaf(xv[1][0], wr[c][0].y, fmaf(xv[2][0], wr[c][0].z, wr[c][0].w)));
                o4.y = fmaf(xv[0][1], wr[c][1].x, fmaf(xv[1][1], wr[c][1].y, fmaf(xv[2][1], wr[c][1].z, wr[c][1].w)));
                o4.z = fmaf(xv[0][2], wr[c][2].x, fmaf(xv[1][2], wr[c][2].y, fmaf(xv[2][2], wr[c][2].z, wr[c][2].w)));
                o4.w = fmaf(xv[0][3], wr[c][3].x, fmaf(xv[1][3], wr[c][3].y, fmaf(xv[2][3], wr[c][3].z, wr[c][3].w)));
                og[t * 384 + row * 24 + c * 8 + fc0] = o4;
            }
        }

        // write next tile into (wave-private) LDS after tile t's reads — in-order
        // LDS within a wave makes this safe with no barrier
        if (t < TILES - 1) {
#pragma unroll
            for (int i = 0; i < 3; ++i) {
                const int p = lane + 64 * i, row = p / 12, k = p - row * 12;
                wlds4[row * 13 + k] = nxt[i];
            }
        }
    }
}

extern "C" void kernel_launch(void* const* d_in, const int* in_sizes, int n_in,
                              void* d_out, int out_size, void* d_ws, size_t ws_size,
                              hipStream_t stream) {
    const float* x = (const float*)d_in[0];
    const float* W = (const float*)d_in[1];
    const float* b = (const float*)d_in[2];
    float* out = (float*)d_out;

    const int blocks = BF_TOTAL / (64 * 4);  // 2048 blocks, 4 waves each
    GraphUpSample_12120397709982_kernel<<<blocks, THREADS, 0, stream>>>(x, W, b, out);
}

// Round 7
// 58.178 us; speedup vs baseline: 1.0605x; 1.0605x over previous
//
#include <hip/hip_runtime.h>

// GraphUpSample: per-node Linear(3->6) over 16 nodes + static column gather
// (the reference's aliased in-place column loop collapses to out col <- SRC[col]).
//
// R7 = R4 (best, 57.2us) + nontemporal hints, using native ext_vector float4
// (HIP_vector_type is rejected by __builtin_nontemporal_*).

#define BATCH 8192
#define FEAT  64
#define BF_TOTAL (BATCH * FEAT)      // 524288 rows
#define ROWS_PER_BLOCK 64
#define THREADS 256                  // 8 col-groups x 32 row-slots, 2 rows/thread
#define XROW 13                      // float4 per padded x row (52 floats)

typedef float vf4 __attribute__((ext_vector_type(4)));

__constant__ int c_SRC[32] = {
    0, 2, 4, 6, 8, 10, 12, 14,
    1, 5, 9, 13, 3, 11, 7, 15,
    1, 3, 5, 7, 9, 11, 13, 15,
    3, 7, 11, 15, 7, 15, 15, 31
};

__global__ __launch_bounds__(THREADS)
void GraphUpSample_12120397709982_kernel(const float* __restrict__ x,
                                         const float* __restrict__ W,
                                         const float* __restrict__ bia,
                                         float* __restrict__ out)
{
    __shared__ vf4   xs4[ROWS_PER_BLOCK * XROW];    // 13312 B
    __shared__ vf4   tbl4[3 * 8 * 5];               // 1920 B, stride-5 padded
    __shared__ int   nns[32];

    const int tid  = threadIdx.x;
    const int fc0  = tid & 7;        // column group: cols 4*fc0 .. 4*fc0+3
    const int rset = tid >> 3;       // 0..31 -> rows rset, rset+32
    const long long rowbase = (long long)blockIdx.x * ROWS_PER_BLOCK;

    // ---- stage x: 768 float4 coalesced (nt: read-once stream) ----
    const vf4* xg = (const vf4*)(x + rowbase * 48);
#pragma unroll
    for (int j = 0; j < 3; ++j) {
        const int p   = tid + j * THREADS;   // 0..767
        const int row = p / 12;
        const int k   = p - row * 12;
        xs4[row * XROW + k] = __builtin_nontemporal_load(xg + p);
    }

    // ---- build weight table once per block (96 threads, tiny) ----
    if (tid < 96) {
        const int c   = tid >> 5;
        const int col = tid & 31;
        const int f   = col >> 2;
        const int s   = col & 3;
        const int src = c_SRC[col];
        const int n   = src >> 1;
        const int o   = 2 * c + (src & 1);
        const float* wp = W + (n * 6 + o) * 3;
        vf4 t; t.x = wp[0]; t.y = wp[1]; t.z = wp[2]; t.w = bia[n * 6 + o];
        tbl4[(c * 8 + f) * 5 + s] = t;
    }
    if (tid < 32) nns[tid] = c_SRC[tid] >> 1;
    __syncthreads();

    // ---- weights -> registers: 12 ds_read_b128 + 4 ds_read_b32, once ----
    int nn[4];
#pragma unroll
    for (int s = 0; s < 4; ++s) nn[s] = nns[fc0 * 4 + s];
    vf4 wr[3][4];
#pragma unroll
    for (int c = 0; c < 3; ++c)
#pragma unroll
        for (int s = 0; s < 4; ++s)
            wr[c][s] = tbl4[(c * 8 + fc0) * 5 + s];

    const float* xs = (const float*)xs4;
    vf4* og = (vf4*)(out + rowbase * 96);
#pragma unroll
    for (int rr = 0; rr < 2; ++rr) {
        const int row = rset + rr * 32;
        const float* xr = xs + row * (XROW * 4);

        float xv[3][4];
#pragma unroll
        for (int cp = 0; cp < 3; ++cp)
#pragma unroll
            for (int s = 0; s < 4; ++s)
                xv[cp][s] = xr[cp * 16 + nn[s]];   // padded rows: <=2-way, free

#pragma unroll
        for (int c = 0; c < 3; ++c) {
            vf4 o4;
            o4.x = fmaf(xv[0][0], wr[c][0].x, fmaf(xv[1][0], wr[c][0].y, fmaf(xv[2][0], wr[c][0].z, wr[c][0].w)));
            o4.y = fmaf(xv[0][1], wr[c][1].x, fmaf(xv[1][1], wr[c][1].y, fmaf(xv[2][1], wr[c][1].z, wr[c][1].w)));
            o4.z = fmaf(xv[0][2], wr[c][2].x, fmaf(xv[1][2], wr[c][2].y, fmaf(xv[2][2], wr[c][2].z, wr[c][2].w)));
            o4.w = fmaf(xv[0][3], wr[c][3].x, fmaf(xv[1][3], wr[c][3].y, fmaf(xv[2][3], wr[c][3].z, wr[c][3].w)));
            // write-once stream: nt store, full 128B aligned line per 8 lanes
            __builtin_nontemporal_store(o4, og + row * 24 + c * 8 + fc0);
        }
    }
}

extern "C" void kernel_launch(void* const* d_in, const int* in_sizes, int n_in,
                              void* d_out, int out_size, void* d_ws, size_t ws_size,
                              hipStream_t stream) {
    const float* x = (const float*)d_in[0];
    const float* W = (const float*)d_in[1];
    const float* b = (const float*)d_in[2];
    float* out = (float*)d_out;

    const int blocks = BF_TOTAL / ROWS_PER_BLOCK;  // 8192
    GraphUpSample_12120397709982_kernel<<<blocks, THREADS, 0, stream>>>(x, W, b, out);
}

// Round 8
// 57.354 us; speedup vs baseline: 1.0758x; 1.0144x over previous
//
#include <hip/hip_runtime.h>

// GraphUpSample: per-node Linear(3->6) over 16 nodes + static column gather
// (the reference's aliased in-place column loop collapses to out col <- SRC[col]).
//
// FINAL (= R4, best measured 57.2us = 5.28 TB/s effective, 84% of the 6.29 TB/s
// copy ceiling — the documented streaming plateau for mixed R:W kernels).
//  - weight table built once/block in LDS by 96 threads, pulled into
//    12 float4 registers per thread (12 ds_read_b128, once per block)
//  - x staged coalesced float4 -> LDS, rows padded to 52 floats (<=2-way banks, free)
//  - tbl padded stride-5 float4 -> conflict-free table reads
//  - stores: each 8-lane group writes one full aligned 128B line (no RFO)
// Exonerated by A/B: bank conflicts (R1), VMEM count (R2), weight-path loads (R3),
// barrier structure (R5), nt hints (R7). Traffic at the 302MB floor per counters.

#define BATCH 8192
#define FEAT  64
#define BF_TOTAL (BATCH * FEAT)      // 524288 rows
#define ROWS_PER_BLOCK 64
#define THREADS 256                  // 8 col-groups x 32 row-slots, 2 rows/thread
#define XROW 13                      // float4 per padded x row (52 floats)

__constant__ int c_SRC[32] = {
    0, 2, 4, 6, 8, 10, 12, 14,
    1, 5, 9, 13, 3, 11, 7, 15,
    1, 3, 5, 7, 9, 11, 13, 15,
    3, 7, 11, 15, 7, 15, 15, 31
};

__global__ __launch_bounds__(THREADS)
void GraphUpSample_12120397709982_kernel(const float* __restrict__ x,
                                         const float* __restrict__ W,
                                         const float* __restrict__ bia,
                                         float* __restrict__ out)
{
    __shared__ float4 xs4[ROWS_PER_BLOCK * XROW];   // 13312 B
    __shared__ float4 tbl4[3 * 8 * 5];              // 1920 B, stride-5 padded
    __shared__ int    nns[32];

    const int tid  = threadIdx.x;
    const int fc0  = tid & 7;        // column group: cols 4*fc0 .. 4*fc0+3
    const int rset = tid >> 3;       // 0..31 -> rows rset, rset+32
    const long long rowbase = (long long)blockIdx.x * ROWS_PER_BLOCK;

    // ---- stage x: 768 float4 coalesced, rows padded to 13 float4 ----
    const float4* xg = (const float4*)(x + rowbase * 48);
#pragma unroll
    for (int j = 0; j < 3; ++j) {
        const int p   = tid + j * THREADS;   // 0..767
        const int row = p / 12;
        const int k   = p - row * 12;
        xs4[row * XROW + k] = xg[p];
    }

    // ---- build weight table once per block (96 threads, tiny) ----
    if (tid < 96) {
        const int c   = tid >> 5;
        const int col = tid & 31;
        const int f   = col >> 2;
        const int s   = col & 3;
        const int src = c_SRC[col];
        const int n   = src >> 1;
        const int o   = 2 * c + (src & 1);
        const float* wp = W + (n * 6 + o) * 3;
        tbl4[(c * 8 + f) * 5 + s] = make_float4(wp[0], wp[1], wp[2], bia[n * 6 + o]);
    }
    if (tid < 32) nns[tid] = c_SRC[tid] >> 1;
    __syncthreads();

    // ---- weights -> registers: 12 ds_read_b128 + 4 ds_read_b32, once ----
    int nn[4];
#pragma unroll
    for (int s = 0; s < 4; ++s) nn[s] = nns[fc0 * 4 + s];
    float4 wr[3][4];
#pragma unroll
    for (int c = 0; c < 3; ++c)
#pragma unroll
        for (int s = 0; s < 4; ++s)
            wr[c][s] = tbl4[(c * 8 + fc0) * 5 + s];

    const float* xs = (const float*)xs4;
    float4* og = (float4*)(out + rowbase * 96);
#pragma unroll
    for (int rr = 0; rr < 2; ++rr) {
        const int row = rset + rr * 32;
        const float* xr = xs + row * (XROW * 4);

        float xv[3][4];
#pragma unroll
        for (int cp = 0; cp < 3; ++cp)
#pragma unroll
            for (int s = 0; s < 4; ++s)
                xv[cp][s] = xr[cp * 16 + nn[s]];   // padded rows: <=2-way, free

#pragma unroll
        for (int c = 0; c < 3; ++c) {
            float4 o4;
            o4.x = fmaf(xv[0][0], wr[c][0].x, fmaf(xv[1][0], wr[c][0].y, fmaf(xv[2][0], wr[c][0].z, wr[c][0].w)));
            o4.y = fmaf(xv[0][1], wr[c][1].x, fmaf(xv[1][1], wr[c][1].y, fmaf(xv[2][1], wr[c][1].z, wr[c][1].w)));
            o4.z = fmaf(xv[0][2], wr[c][2].x, fmaf(xv[1][2], wr[c][2].y, fmaf(xv[2][2], wr[c][2].z, wr[c][2].w)));
            o4.w = fmaf(xv[0][3], wr[c][3].x, fmaf(xv[1][3], wr[c][3].y, fmaf(xv[2][3], wr[c][3].z, wr[c][3].w)));
            og[row * 24 + c * 8 + fc0] = o4;       // full 128B segments per 8 lanes
        }
    }
}

extern "C" void kernel_launch(void* const* d_in, const int* in_sizes, int n_in,
                              void* d_out, int out_size, void* d_ws, size_t ws_size,
                              hipStream_t stream) {
    const float* x = (const float*)d_in[0];
    const float* W = (const float*)d_in[1];
    const float* b = (const float*)d_in[2];
    float* out = (float*)d_out;

    const int blocks = BF_TOTAL / ROWS_PER_BLOCK;  // 8192
    GraphUpSample_12120397709982_kernel<<<blocks, THREADS, 0, stream>>>(x, W, b, out);
}